// Round 1
// baseline (1919.930 us; speedup 1.0000x reference)
//
#include <hip/hip_runtime.h>
#include <hip/hip_bf16.h>
#include <math.h>

// Problem constants (match reference)
#define ITEMS 2048   // B*N = 32*64
#define SEQ   64     // N
#define DM    128    // D_MODEL
#define DFF   512    // D_FF
#define ATT_OFF 131072  // 32*64*64, offset of avg_h_c_N in d_out

__device__ __forceinline__ float wsum(float v){
  #pragma unroll
  for (int off = 1; off < 64; off <<= 1) v += __shfl_xor(v, off);
  return v;
}

__global__ __launch_bounds__(256) void vicsek_fused(
    const float* __restrict__ agent_infos,
    const int*   __restrict__ nmask,
    const float* __restrict__ W_emb, const float* __restrict__ b_emb,
    const float* __restrict__ Wq,    const float* __restrict__ Wk,
    const float* __restrict__ Wv,    const float* __restrict__ Wo,
    const float* __restrict__ ln1g,  const float* __restrict__ ln1b,
    const float* __restrict__ W1,    const float* __restrict__ b1,
    const float* __restrict__ W2,    const float* __restrict__ b2,
    const float* __restrict__ ln2g,  const float* __restrict__ ln2b,
    const float* __restrict__ Uq,    const float* __restrict__ Uk,
    const float* __restrict__ Uv,    const float* __restrict__ Uo,
    const float* __restrict__ ln3g,  const float* __restrict__ ln3b,
    const float* __restrict__ W3,    const float* __restrict__ b3,
    const float* __restrict__ W4,    const float* __restrict__ b4,
    const float* __restrict__ ln4g,  const float* __restrict__ ln4b,
    const float* __restrict__ Wgq,   const float* __restrict__ Wgk,
    float* __restrict__ out,         float* __restrict__ ws_hc)
{
  // LDS arena (~60 KB -> 2 blocks/CU)
  __shared__ float Xs[SEQ*129];     // x tile, padded stride 129 (33 KB)
  __shared__ float sS[4096];        // QKV per-head (3x1024) / FFN hidden (8x512)
  __shared__ float sOh[SEQ*16];     // per-head attention output
  __shared__ float sFout[8*DM];     // FFN output chunk
  __shared__ float sHc[DM], sQv[DM], sOv[DM], sYv[DM], sY2[DM];
  __shared__ float pbuf[SEQ], neighf[SEQ], padf[SEQ];
  __shared__ float cnt_s;

  const int item = blockIdx.x;
  const int tid  = threadIdx.x;
  const int lane = tid & 63;
  const int wave = tid >> 6;

  // ---- neighbor flags ----
  if (tid < SEQ){
    int m = nmask[item*SEQ + tid];
    neighf[tid] = m ? 1.f : 0.f;
    padf[tid]   = m ? 0.f : 1.f;   // reference: pad = ~neigh
  }
  __syncthreads();
  if (tid == 0){
    float c = 0.f;
    for (int j = 0; j < SEQ; j++) c += neighf[j];
    cnt_s = c;                      // reference: cnt = neigh.sum()
  }

  // ---- Stage A: embed  X = src @ W_emb + b_emb ----
  const float* src = agent_infos + (size_t)item*SEQ*6;
  for (int e = tid; e < SEQ*DM; e += 256){
    int r = e >> 7, c = e & 127;
    float a = b_emb[c];
    #pragma unroll
    for (int k = 0; k < 6; k++) a += src[r*6+k]*W_emb[k*DM+c];
    Xs[r*129+c] = a;
  }
  __syncthreads();

  // ---- Stage B: self-MHA, accumulate attn@Wo into racc ----
  float racc[32];
  #pragma unroll
  for (int i = 0; i < 32; i++) racc[i] = 0.f;

  const int dq = tid & 15, rb = tid >> 4;     // QKV mapping: 16 d x 16 row-groups
  const int cW = tid & 127, rhalf = tid >> 7; // Wo mapping: col + row-half

  for (int h = 0; h < 8; h++){
    // Q,K,V for head h (4-row register blocking per weight load)
    {
      int col = h*16 + dq;
      float aq[4]={0,0,0,0}, ak[4]={0,0,0,0}, av[4]={0,0,0,0};
      for (int e = 0; e < DM; e++){
        float wq_ = Wq[e*DM+col], wk_ = Wk[e*DM+col], wv_ = Wv[e*DM+col];
        #pragma unroll
        for (int u = 0; u < 4; u++){
          float xv = Xs[(rb+16*u)*129+e];
          aq[u] += xv*wq_; ak[u] += xv*wk_; av[u] += xv*wv_;
        }
      }
      #pragma unroll
      for (int u = 0; u < 4; u++){
        int r = rb+16*u;
        sS[       r*16+dq] = aq[u];
        sS[1024 + r*16+dq] = ak[u];
        sS[2048 + r*16+dq] = av[u];
      }
    }
    __syncthreads();

    // scores + masked softmax + P@V : 4 threads per row, 16 cols each
    {
      int r = tid >> 2, sub = tid & 3;
      float qreg[16];
      #pragma unroll
      for (int d2 = 0; d2 < 16; d2++) qreg[d2] = sS[r*16+d2];
      float mrow = neighf[r];
      float p[16]; float mx = -3.0e38f;
      #pragma unroll
      for (int jj = 0; jj < 16; jj++){
        int j = sub*16+jj;
        float s = 0.f;
        #pragma unroll
        for (int d2 = 0; d2 < 16; d2++) s += qreg[d2]*sS[1024 + j*16+d2];
        s *= 0.25f;                                   // 1/sqrt(16)
        if (mrow < 0.5f || neighf[j] < 0.5f) s = -1.0e9f;
        p[jj] = s;
        mx = fmaxf(mx, s);
      }
      mx = fmaxf(mx, __shfl_xor(mx, 1));
      mx = fmaxf(mx, __shfl_xor(mx, 2));
      float sum = 0.f;
      #pragma unroll
      for (int jj = 0; jj < 16; jj++){ p[jj] = __expf(p[jj]-mx); sum += p[jj]; }
      sum += __shfl_xor(sum, 1);
      sum += __shfl_xor(sum, 2);
      float inv = 1.f/sum;
      float od[16];
      #pragma unroll
      for (int d2 = 0; d2 < 16; d2++) od[d2] = 0.f;
      #pragma unroll
      for (int jj = 0; jj < 16; jj++){
        float pj = p[jj]*inv;
        int j = sub*16+jj;
        #pragma unroll
        for (int d2 = 0; d2 < 16; d2++) od[d2] += pj*sS[2048 + j*16+d2];
      }
      #pragma unroll
      for (int d2 = 0; d2 < 16; d2++){
        od[d2] += __shfl_xor(od[d2], 1);
        od[d2] += __shfl_xor(od[d2], 2);
      }
      #pragma unroll
      for (int d2 = 0; d2 < 4; d2++){
        int dd = sub*4+d2;
        sOh[r*16+dd] = od[dd];
      }
    }
    __syncthreads();

    // racc += Oh @ Wo[h*16:(h+1)*16, :]
    {
      float wrow[16];
      #pragma unroll
      for (int dd = 0; dd < 16; dd++) wrow[dd] = Wo[(h*16+dd)*DM + cW];
      #pragma unroll
      for (int i = 0; i < 32; i++){
        int r = rhalf + 2*i;
        float a = racc[i];
        #pragma unroll
        for (int dd = 0; dd < 16; dd++) a += sOh[r*16+dd]*wrow[dd];
        racc[i] = a;
      }
    }
    __syncthreads();
  }

  // residual + LN1
  #pragma unroll
  for (int i = 0; i < 32; i++){
    int r = rhalf + 2*i;
    Xs[r*129+cW] += racc[i];
  }
  __syncthreads();
  for (int r = wave; r < SEQ; r += 4){
    float v0 = Xs[r*129+lane], v1 = Xs[r*129+lane+64];
    float m  = wsum(v0+v1) * (1.f/128.f);
    float d0 = v0-m, d1 = v1-m;
    float var = wsum(d0*d0+d1*d1) * (1.f/128.f);
    float inv = rsqrtf(var + 1e-5f);
    Xs[r*129+lane]    = d0*inv*ln1g[lane]    + ln1b[lane];
    Xs[r*129+lane+64] = d1*inv*ln1g[lane+64] + ln1b[lane+64];
  }
  __syncthreads();

  // ---- Stage C: FFN1 + LN2, 8 groups of 8 rows ----
  for (int g = 0; g < 8; g++){
    int jA = tid, jB = tid + 256;
    float b1a = b1[jA], b1b = b1[jB];
    float ha[8] = {0,0,0,0,0,0,0,0}, hb[8] = {0,0,0,0,0,0,0,0};
    for (int e = 0; e < DM; e++){
      float w1a = W1[e*DFF+jA], w1b = W1[e*DFF+jB];
      #pragma unroll
      for (int u = 0; u < 8; u++){
        float xv = Xs[(g*8+u)*129+e];
        ha[u] += xv*w1a; hb[u] += xv*w1b;
      }
    }
    #pragma unroll
    for (int u = 0; u < 8; u++){
      sS[u*DFF + jA] = fmaxf(ha[u]+b1a, 0.f);
      sS[u*DFF + jB] = fmaxf(hb[u]+b1b, 0.f);
    }
    __syncthreads();

    int c = tid & 127, u0 = (tid >> 7)*4;
    float o[4] = {0,0,0,0};
    for (int j = 0; j < DFF; j++){
      float w2 = W2[j*DM+c];
      #pragma unroll
      for (int uu = 0; uu < 4; uu++) o[uu] += sS[(u0+uu)*DFF + j]*w2;
    }
    float b2v = b2[c];
    #pragma unroll
    for (int uu = 0; uu < 4; uu++) sFout[(u0+uu)*DM + c] = o[uu] + b2v;
    __syncthreads();

    #pragma unroll
    for (int rr = 0; rr < 2; rr++){
      int u = wave*2 + rr;
      int r = g*8 + u;
      float v0 = Xs[r*129+lane]    + sFout[u*DM+lane];
      float v1 = Xs[r*129+lane+64] + sFout[u*DM+lane+64];
      float m  = wsum(v0+v1) * (1.f/128.f);
      float d0 = v0-m, d1 = v1-m;
      float var = wsum(d0*d0+d1*d1) * (1.f/128.f);
      float inv = rsqrtf(var + 1e-5f);
      Xs[r*129+lane]    = d0*inv*ln2g[lane]    + ln2b[lane];
      Xs[r*129+lane+64] = d1*inv*ln2g[lane+64] + ln2b[lane+64];
    }
    __syncthreads();
  }

  // ---- Stage D: h_c = (x * pad).sum(rows)/cnt ----
  if (tid < DM){
    float a = 0.f;
    for (int r = 0; r < SEQ; r++) a += Xs[r*129+tid]*padf[r];
    sHc[tid] = a / cnt_s;
  }
  __syncthreads();
  if (tid < DM) ws_hc[(size_t)item*DM + tid] = sHc[tid];

  // ---- Stage E: cross-attention (1 query) ----
  if (tid < DM){
    float a = 0.f;
    for (int e = 0; e < DM; e++) a += sHc[e]*Uq[e*DM+tid];
    sQv[tid] = a;
  }
  __syncthreads();

  for (int h = 0; h < 8; h++){
    // K_h, V_h for this head
    {
      int col = h*16 + dq;
      float ak[4]={0,0,0,0}, av[4]={0,0,0,0};
      for (int e = 0; e < DM; e++){
        float uk_ = Uk[e*DM+col], uv_ = Uv[e*DM+col];
        #pragma unroll
        for (int u = 0; u < 4; u++){
          float xv = Xs[(rb+16*u)*129+e];
          ak[u] += xv*uk_; av[u] += xv*uv_;
        }
      }
      #pragma unroll
      for (int u = 0; u < 4; u++){
        int r = rb+16*u;
        sS[       r*16+dq] = ak[u];
        sS[1024 + r*16+dq] = av[u];
      }
    }
    __syncthreads();
    // scores + softmax over 64 keys (wave 0)
    if (wave == 0){
      float s = 0.f;
      #pragma unroll
      for (int d2 = 0; d2 < 16; d2++) s += sQv[h*16+d2]*sS[lane*16+d2];
      s *= 0.25f;
      if (neighf[lane] < 0.5f) s = -1.0e9f;
      float mx = s;
      #pragma unroll
      for (int off = 1; off < 64; off <<= 1) mx = fmaxf(mx, __shfl_xor(mx, off));
      float p = __expf(s-mx);
      float sum = wsum(p);
      pbuf[lane] = p/sum;
    }
    __syncthreads();
    if (tid < 16){
      float a = 0.f;
      for (int j = 0; j < SEQ; j++) a += pbuf[j]*sS[1024 + j*16 + tid];
      sOv[h*16+tid] = a;
    }
    __syncthreads();
  }

  // y = LN3(h_c + o @ Uo)
  if (tid < DM){
    float a = 0.f;
    for (int e = 0; e < DM; e++) a += sOv[e]*Uo[e*DM+tid];
    sYv[tid] = sHc[tid] + a;
  }
  __syncthreads();
  if (wave == 0){
    float v0 = sYv[lane], v1 = sYv[lane+64];
    float m  = wsum(v0+v1) * (1.f/128.f);
    float d0 = v0-m, d1 = v1-m;
    float var = wsum(d0*d0+d1*d1) * (1.f/128.f);
    float inv = rsqrtf(var + 1e-5f);
    sYv[lane]    = d0*inv*ln3g[lane]    + ln3b[lane];
    sYv[lane+64] = d1*inv*ln3g[lane+64] + ln3b[lane+64];
  }
  __syncthreads();

  // ---- Stage F: FFN2 + LN4 ----
  for (int j = tid; j < DFF; j += 256){
    float a = b3[j];
    for (int e = 0; e < DM; e++) a += sYv[e]*W3[e*DFF+j];
    sS[j] = fmaxf(a, 0.f);
  }
  __syncthreads();
  if (tid < DM){
    float a = b4[tid];
    for (int j = 0; j < DFF; j++) a += sS[j]*W4[j*DM+tid];
    sY2[tid] = sYv[tid] + a;
  }
  __syncthreads();
  if (wave == 0){
    float v0 = sY2[lane], v1 = sY2[lane+64];
    float m  = wsum(v0+v1) * (1.f/128.f);
    float d0 = v0-m, d1 = v1-m;
    float var = wsum(d0*d0+d1*d1) * (1.f/128.f);
    float inv = rsqrtf(var + 1e-5f);
    sY2[lane]    = d0*inv*ln4g[lane]    + ln4b[lane];
    sY2[lane+64] = d1*inv*ln4g[lane+64] + ln4b[lane+64];
  }
  __syncthreads();

  // ---- Stage G: gating ----
  // gq = y2 @ Wg_q  (reuse sQv)
  if (tid < DM){
    float a = 0.f;
    for (int e = 0; e < DM; e++) a += sY2[e]*Wgq[e*DM+tid];
    sQv[tid] = a;
  }
  __syncthreads();
  // w[e] = Wg_k[e,:] . gq  (reuse sOv)
  if (tid < DM){
    float a = 0.f;
    for (int d2 = 0; d2 < DM; d2++) a += Wgk[tid*DM+d2]*sQv[d2];
    sOv[tid] = a;
  }
  __syncthreads();
  // logit_j = (x[j] . w) / sqrt(128); prob = neigh ? sigmoid : 0
  if (tid < SEQ){
    float a = 0.f;
    for (int e = 0; e < DM; e++) a += Xs[tid*129+e]*sOv[e];
    a *= 0.08838834764831845f;   // 1/sqrt(128)
    float prob = (neighf[tid] > 0.5f) ? (1.f/(1.f+__expf(-a))) : 0.f;
    out[(size_t)item*SEQ + tid] = prob;
  }
}

__global__ void avg_hc_kernel(const float* __restrict__ ws_hc,
                              const int* __restrict__ pmask,
                              float* __restrict__ out)
{
  int b = blockIdx.x, d = threadIdx.x;   // 32 blocks x 128 threads
  float a = 0.f;
  for (int n = 0; n < SEQ; n++) a += ws_hc[(size_t)(b*SEQ+n)*DM + d];
  float na = 0.f;
  for (int n = 0; n < SEQ; n++) na += (float)pmask[b*SEQ+n];
  out[ATT_OFF + b*DM + d] = a/na;
}

extern "C" void kernel_launch(void* const* d_in, const int* in_sizes, int n_in,
                              void* d_out, int out_size, void* d_ws, size_t ws_size,
                              hipStream_t stream)
{
  const float* agent_infos = (const float*)d_in[0];
  const int*   nmask       = (const int*)  d_in[1];
  const int*   pmask       = (const int*)  d_in[2];
  // d_in[3] is_from_my_env: unused by reference
  const float* W_emb = (const float*)d_in[4];
  const float* b_emb = (const float*)d_in[5];
  const float* Wq    = (const float*)d_in[6];
  const float* Wk    = (const float*)d_in[7];
  const float* Wv    = (const float*)d_in[8];
  const float* Wo    = (const float*)d_in[9];
  const float* ln1g  = (const float*)d_in[10];
  const float* ln1b  = (const float*)d_in[11];
  const float* W1    = (const float*)d_in[12];
  const float* b1    = (const float*)d_in[13];
  const float* W2    = (const float*)d_in[14];
  const float* b2    = (const float*)d_in[15];
  const float* ln2g  = (const float*)d_in[16];
  const float* ln2b  = (const float*)d_in[17];
  const float* Uq    = (const float*)d_in[18];
  const float* Uk    = (const float*)d_in[19];
  const float* Uv    = (const float*)d_in[20];
  const float* Uo    = (const float*)d_in[21];
  const float* ln3g  = (const float*)d_in[22];
  const float* ln3b  = (const float*)d_in[23];
  const float* W3    = (const float*)d_in[24];
  const float* b3    = (const float*)d_in[25];
  const float* W4    = (const float*)d_in[26];
  const float* b4    = (const float*)d_in[27];
  const float* ln4g  = (const float*)d_in[28];
  const float* ln4b  = (const float*)d_in[29];
  const float* Wgq   = (const float*)d_in[30];
  const float* Wgk   = (const float*)d_in[31];

  float* out   = (float*)d_out;
  float* ws_hc = (float*)d_ws;   // 2048*128 floats = 1 MB

  vicsek_fused<<<ITEMS, 256, 0, stream>>>(
      agent_infos, nmask, W_emb, b_emb, Wq, Wk, Wv, Wo, ln1g, ln1b,
      W1, b1, W2, b2, ln2g, ln2b, Uq, Uk, Uv, Uo, ln3g, ln3b,
      W3, b3, W4, b4, ln4g, ln4b, Wgq, Wgk, out, ws_hc);

  avg_hc_kernel<<<32, 128, 0, stream>>>(ws_hc, pmask, out);
}

// Round 2
// 1241.295 us; speedup vs baseline: 1.5467x; 1.5467x over previous
//
#include <hip/hip_runtime.h>
#include <hip/hip_bf16.h>
#include <math.h>

#define ITEMS 2048
#define SEQ   64
#define DM    128
#define DFF   512
#define ATT_OFF 131072
#define XST   152   // bf16 row stride: 304B = 19*16 -> aligned b128, 2-way banks (free)

typedef unsigned short u16;
typedef __attribute__((ext_vector_type(8))) short short8v;
typedef __attribute__((ext_vector_type(4))) float float4v;

#define MFMA16(a,b,c) __builtin_amdgcn_mfma_f32_16x16x32_bf16(a,b,c,0,0,0)

// ws layout (bf16 elements): WqT 0, WkT 16384, WvT 32768, WoT 49152,
// UkT 65536, UvT 81920, W1T 98304 (512x128), W2T 163840 (128x512). total 229376 elems.

__device__ __forceinline__ u16 f2b(float f){
  union { float f; unsigned u; } v; v.f = f;
  unsigned r = (v.u + 0x7fffu + ((v.u >> 16) & 1u)) >> 16;
  return (u16)r;
}
__device__ __forceinline__ float b2f(u16 h){
  union { unsigned u; float f; } v; v.u = ((unsigned)h) << 16;
  return v.f;
}
__device__ __forceinline__ float wsum(float v){
  #pragma unroll
  for (int off = 1; off < 64; off <<= 1) v += __shfl_xor(v, off);
  return v;
}
__device__ __forceinline__ void ln_vec(float* v, const float* g, const float* b, int lane){
  float v0 = v[lane], v1 = v[lane+64];
  float m  = wsum(v0+v1) * (1.f/128.f);
  float d0 = v0-m, d1 = v1-m;
  float var = wsum(d0*d0+d1*d1) * (1.f/128.f);
  float inv = rsqrtf(var + 1e-5f);
  v[lane]    = d0*inv*g[lane]    + b[lane];
  v[lane+64] = d1*inv*g[lane+64] + b[lane+64];
}

__global__ void prep_all(const float* __restrict__ Wq, const float* __restrict__ Wk,
                         const float* __restrict__ Wv, const float* __restrict__ Wo,
                         const float* __restrict__ Uk, const float* __restrict__ Uv,
                         const float* __restrict__ W1, const float* __restrict__ W2,
                         u16* __restrict__ wts){
  int idx = blockIdx.x*256 + threadIdx.x;
  if (idx >= 229376) return;
  if (idx < 98304){                       // six 128x128 -> WT[out][in]
    int wsel = idx >> 14, r = idx & 16383;
    const float* tab[6] = {Wq,Wk,Wv,Wo,Uk,Uv};
    int o = r >> 7, i = r & 127;
    wts[idx] = f2b(tab[wsel][i*128 + o]);
  } else if (idx < 163840){               // W1T [512][128]
    int r = idx - 98304;
    int o = r >> 7, i = r & 127;
    wts[idx] = f2b(W1[i*512 + o]);
  } else {                                // W2T [128][512]
    int r = idx - 163840;
    int o = r >> 9, i = r & 511;
    wts[idx] = f2b(W2[i*128 + o]);
  }
}

__global__ void init_avg(float* __restrict__ out){
  out[ATT_OFF + blockIdx.x*256 + threadIdx.x] = 0.f;   // grid 16 x 256 = 4096
}

__global__ __launch_bounds__(256) void vicsek_fused(
    const float* __restrict__ agent_infos,
    const int*   __restrict__ nmask,
    const int*   __restrict__ pmask,
    const u16*   __restrict__ wts,
    const float* __restrict__ W_emb, const float* __restrict__ b_emb,
    const float* __restrict__ ln1g,  const float* __restrict__ ln1b,
    const float* __restrict__ b1,    const float* __restrict__ b2,
    const float* __restrict__ ln2g,  const float* __restrict__ ln2b,
    const float* __restrict__ Uq,    const float* __restrict__ Uo,
    const float* __restrict__ ln3g,  const float* __restrict__ ln3b,
    const float* __restrict__ W3,    const float* __restrict__ b3,
    const float* __restrict__ W4,    const float* __restrict__ b4,
    const float* __restrict__ ln4g,  const float* __restrict__ ln4b,
    const float* __restrict__ Wgq,   const float* __restrict__ Wgk,
    float* __restrict__ out)
{
  __shared__ __align__(16) u16 Xs[SEQ*XST];   // activations bf16
  __shared__ __align__(16) u16 Bb[SEQ*XST];   // attn-O / FFN hidden chunk bf16
  __shared__ float sQ[SEQ*17];                // also reused as fp32 FFN buffer later
  __shared__ float sK[SEQ*17];
  __shared__ float sV[SEQ*17];
  __shared__ float sHc[DM], sQv[DM], sOv[DM], sYv[DM], sY2[DM];
  __shared__ float pbuf[SEQ], neighf[SEQ], padf[SEQ];
  __shared__ float cnt_s, numag_s;

  const int item = blockIdx.x;
  const int tid  = threadIdx.x;
  const int lane = tid & 63;
  const int w    = tid >> 6;
  const int row0 = w*16;
  const int arow = lane & 15;    // frag row (A) / col (B,C)
  const int akg  = lane >> 4;    // k-group
  const int crow0 = row0 + akg*4;
  const int ccol  = arow;

  const u16* aXp = Xs + (row0 + arow)*XST + akg*8;
  const u16* aBp = Bb + (row0 + arow)*XST + akg*8;

  const u16* WqT = wts;          const u16* WkT = wts + 16384;
  const u16* WvT = wts + 32768;  const u16* WoT = wts + 49152;
  const u16* UkT = wts + 65536;  const u16* UvT = wts + 81920;
  const u16* W1T = wts + 98304;  const u16* W2T = wts + 163840;

  auto ldB128 = [&](const u16* WT, int n0, int k0) -> short8v {
    return *(const short8v*)(WT + (n0 + arow)*128 + k0 + akg*8);
  };

  // ---- flags ----
  if (tid < SEQ){
    int m = nmask[item*SEQ + tid];
    neighf[tid] = m ? 1.f : 0.f;
    padf[tid]   = m ? 0.f : 1.f;   // reference: pad = ~neigh
  }
  if (tid == 0){
    float c = 0.f;
    for (int j = 0; j < SEQ; j++) c += nmask[item*SEQ+j] ? 1.f : 0.f;
    cnt_s = c;
  }
  if (tid == 1){
    int b = item >> 6;
    float na = 0.f;
    for (int j = 0; j < SEQ; j++) na += (float)pmask[b*SEQ+j];
    numag_s = na;
  }

  // ---- Stage A: embed ----
  const float* src = agent_infos + (size_t)item*SEQ*6;
  for (int e = tid; e < SEQ*DM; e += 256){
    int r = e >> 7, c = e & 127;
    float a = b_emb[c];
    #pragma unroll
    for (int k = 0; k < 6; k++) a += src[r*6+k]*W_emb[k*DM+c];
    Xs[r*XST + c] = f2b(a);
  }
  __syncthreads();

  // ---- Stage B: self-MHA ----
  short8v aX[4];
  #pragma unroll
  for (int k = 0; k < 4; k++) aX[k] = *(const short8v*)(aXp + k*32);

  for (int h = 0; h < 8; h++){
    float4v aq = {0,0,0,0}, ak = {0,0,0,0}, av = {0,0,0,0};
    #pragma unroll
    for (int k = 0; k < 4; k++){
      short8v a = aX[k];
      aq = MFMA16(a, ldB128(WqT, h*16, k*32), aq);
      ak = MFMA16(a, ldB128(WkT, h*16, k*32), ak);
      av = MFMA16(a, ldB128(WvT, h*16, k*32), av);
    }
    #pragma unroll
    for (int i = 0; i < 4; i++){
      sQ[(crow0+i)*17 + ccol] = aq[i];
      sK[(crow0+i)*17 + ccol] = ak[i];
      sV[(crow0+i)*17 + ccol] = av[i];
    }
    __syncthreads();

    {   // masked softmax + P@V : 4 threads/row, 16 keys each
      int r = tid >> 2, sub = tid & 3;
      float qreg[16];
      #pragma unroll
      for (int d = 0; d < 16; d++) qreg[d] = sQ[r*17+d];
      float mrow = neighf[r];
      float p[16]; float mx = -3.0e38f;
      #pragma unroll
      for (int jj = 0; jj < 16; jj++){
        int j = sub*16+jj;
        float s = 0.f;
        #pragma unroll
        for (int d = 0; d < 16; d++) s += qreg[d]*sK[j*17+d];
        s *= 0.25f;
        if (mrow < 0.5f || neighf[j] < 0.5f) s = -1.0e9f;
        p[jj] = s; mx = fmaxf(mx, s);
      }
      mx = fmaxf(mx, __shfl_xor(mx,1)); mx = fmaxf(mx, __shfl_xor(mx,2));
      float sum = 0.f;
      #pragma unroll
      for (int jj = 0; jj < 16; jj++){ p[jj] = __expf(p[jj]-mx); sum += p[jj]; }
      sum += __shfl_xor(sum,1); sum += __shfl_xor(sum,2);
      float inv = 1.f/sum;
      float od[16];
      #pragma unroll
      for (int d = 0; d < 16; d++) od[d] = 0.f;
      #pragma unroll
      for (int jj = 0; jj < 16; jj++){
        float pj = p[jj]*inv; int j = sub*16+jj;
        #pragma unroll
        for (int d = 0; d < 16; d++) od[d] += pj*sV[j*17+d];
      }
      #pragma unroll
      for (int d = 0; d < 16; d++){ od[d] += __shfl_xor(od[d],1); od[d] += __shfl_xor(od[d],2); }
      #pragma unroll
      for (int d = 0; d < 4; d++) Bb[r*XST + h*16 + sub*4 + d] = f2b(od[sub*4+d]);
    }
    __syncthreads();
  }

  // Wo projection + residual (acc init from Xs)
  {
    float4v accW[8];
    #pragma unroll
    for (int t = 0; t < 8; t++)
      #pragma unroll
      for (int i = 0; i < 4; i++)
        accW[t][i] = b2f(Xs[(crow0+i)*XST + t*16 + ccol]);
    #pragma unroll
    for (int k = 0; k < 4; k++){
      short8v a = *(const short8v*)(aBp + k*32);
      #pragma unroll
      for (int t = 0; t < 8; t++)
        accW[t] = MFMA16(a, ldB128(WoT, t*16, k*32), accW[t]);
    }
    #pragma unroll
    for (int t = 0; t < 8; t++)
      #pragma unroll
      for (int i = 0; i < 4; i++)
        Xs[(crow0+i)*XST + t*16 + ccol] = f2b(accW[t][i]);
  }
  // LN1 on own rows
  for (int rr = 0; rr < 16; rr++){
    int r = row0 + rr;
    float v0 = b2f(Xs[r*XST+lane]), v1 = b2f(Xs[r*XST+lane+64]);
    float m  = wsum(v0+v1) * (1.f/128.f);
    float d0 = v0-m, d1 = v1-m;
    float var = wsum(d0*d0+d1*d1) * (1.f/128.f);
    float inv = rsqrtf(var + 1e-5f);
    Xs[r*XST+lane]    = f2b(d0*inv*ln1g[lane]    + ln1b[lane]);
    Xs[r*XST+lane+64] = f2b(d1*inv*ln1g[lane+64] + ln1b[lane+64]);
  }
  __syncthreads();

  // ---- Stage C: FFN (4 chunks of 128), Y accumulator resident ----
  #pragma unroll
  for (int k = 0; k < 4; k++) aX[k] = *(const short8v*)(aXp + k*32);

  float4v accY[8];
  #pragma unroll
  for (int t = 0; t < 8; t++){
    float bb = b2[t*16 + ccol];
    #pragma unroll
    for (int i = 0; i < 4; i++)
      accY[t][i] = bb + b2f(Xs[(crow0+i)*XST + t*16 + ccol]);
  }

  for (int c = 0; c < 4; c++){
    #pragma unroll
    for (int t = 0; t < 8; t++){
      float bb = b1[c*128 + t*16 + ccol];
      float4v acc = {bb,bb,bb,bb};
      #pragma unroll
      for (int k = 0; k < 4; k++)
        acc = MFMA16(aX[k], ldB128(W1T, c*128 + t*16, k*32), acc);
      #pragma unroll
      for (int i = 0; i < 4; i++)
        Bb[(crow0+i)*XST + t*16 + ccol] = f2b(fmaxf(acc[i], 0.f));
    }
    __syncthreads();
    #pragma unroll
    for (int k = 0; k < 4; k++){
      short8v aH = *(const short8v*)(aBp + k*32);
      #pragma unroll
      for (int t = 0; t < 8; t++)
        accY[t] = MFMA16(aH, *(const short8v*)(W2T + (t*16+arow)*512 + c*128 + k*32 + akg*8), accY[t]);
    }
    __syncthreads();
  }
  #pragma unroll
  for (int t = 0; t < 8; t++)
    #pragma unroll
    for (int i = 0; i < 4; i++)
      Xs[(crow0+i)*XST + t*16 + ccol] = f2b(accY[t][i]);
  // LN2 on own rows
  for (int rr = 0; rr < 16; rr++){
    int r = row0 + rr;
    float v0 = b2f(Xs[r*XST+lane]), v1 = b2f(Xs[r*XST+lane+64]);
    float m  = wsum(v0+v1) * (1.f/128.f);
    float d0 = v0-m, d1 = v1-m;
    float var = wsum(d0*d0+d1*d1) * (1.f/128.f);
    float inv = rsqrtf(var + 1e-5f);
    Xs[r*XST+lane]    = f2b(d0*inv*ln2g[lane]    + ln2b[lane]);
    Xs[r*XST+lane+64] = f2b(d1*inv*ln2g[lane+64] + ln2b[lane+64]);
  }
  __syncthreads();

  // ---- Stage D: h_c + global average (atomic) ----
  if (tid < DM){
    float a = 0.f;
    for (int r = 0; r < SEQ; r++) a += b2f(Xs[r*XST+tid])*padf[r];
    a /= cnt_s;
    sHc[tid] = a;
    atomicAdd(&out[ATT_OFF + (item>>6)*DM + tid], a/numag_s);
  }
  __syncthreads();

  // ---- Stage E: cross-attention (1 query) ----
  if (tid < DM){
    float a = 0.f;
    for (int e = 0; e < DM; e++) a += sHc[e]*Uq[e*DM+tid];
    sQv[tid] = a;
  }
  __syncthreads();

  #pragma unroll
  for (int k = 0; k < 4; k++) aX[k] = *(const short8v*)(aXp + k*32);

  for (int h = 0; h < 8; h++){
    float4v ak = {0,0,0,0}, av = {0,0,0,0};
    #pragma unroll
    for (int k = 0; k < 4; k++){
      ak = MFMA16(aX[k], ldB128(UkT, h*16, k*32), ak);
      av = MFMA16(aX[k], ldB128(UvT, h*16, k*32), av);
    }
    #pragma unroll
    for (int i = 0; i < 4; i++){
      sK[(crow0+i)*17 + ccol] = ak[i];
      sV[(crow0+i)*17 + ccol] = av[i];
    }
    __syncthreads();
    if (w == 0){
      float s = 0.f;
      #pragma unroll
      for (int d = 0; d < 16; d++) s += sQv[h*16+d]*sK[lane*17+d];
      s *= 0.25f;
      if (neighf[lane] < 0.5f) s = -1.0e9f;
      float mx = s;
      #pragma unroll
      for (int off = 1; off < 64; off <<= 1) mx = fmaxf(mx, __shfl_xor(mx, off));
      float p = __expf(s-mx);
      float su = wsum(p);
      pbuf[lane] = p/su;
    }
    __syncthreads();
    if (w == 1){
      int d = lane & 15, j0 = (lane>>4)*16;
      float a = 0.f;
      #pragma unroll
      for (int jj = 0; jj < 16; jj++) a += pbuf[j0+jj]*sV[(j0+jj)*17+d];
      a += __shfl_xor(a,16); a += __shfl_xor(a,32);
      if (lane < 16) sOv[h*16+d] = a;
    }
    __syncthreads();
  }

  // y = LN3(h_c + O @ Uo)
  if (tid < DM){
    float a = 0.f;
    for (int e = 0; e < DM; e++) a += sOv[e]*Uo[e*DM+tid];
    sYv[tid] = sHc[tid] + a;
  }
  __syncthreads();
  if (w == 0) ln_vec(sYv, ln3g, ln3b, lane);
  __syncthreads();

  // ---- Stage F: 1-row FFN + LN4 ----
  float* sFF = sQ;   // reuse (>=512 floats)
  for (int j = tid; j < DFF; j += 256){
    float a = b3[j];
    for (int e = 0; e < DM; e++) a += sYv[e]*W3[e*DFF+j];
    sFF[j] = fmaxf(a, 0.f);
  }
  __syncthreads();
  if (tid < DM){
    float a0=0,a1=0,a2=0,a3=0;
    for (int j = 0; j < DFF; j += 4){
      a0 += sFF[j  ]*W4[(j  )*DM+tid];
      a1 += sFF[j+1]*W4[(j+1)*DM+tid];
      a2 += sFF[j+2]*W4[(j+2)*DM+tid];
      a3 += sFF[j+3]*W4[(j+3)*DM+tid];
    }
    sY2[tid] = b4[tid] + sYv[tid] + ((a0+a1)+(a2+a3));
  }
  __syncthreads();
  if (w == 0) ln_vec(sY2, ln4g, ln4b, lane);
  __syncthreads();

  // ---- Stage G: gating ----
  if (tid < DM){
    float a = 0.f;
    for (int e = 0; e < DM; e++) a += sY2[e]*Wgq[e*DM+tid];
    sQv[tid] = a;
  }
  __syncthreads();
  if (tid < DM){
    float a = 0.f;
    for (int d = 0; d < DM; d++) a += Wgk[tid*DM+d]*sQv[d];
    sOv[tid] = a;
  }
  __syncthreads();
  if (tid < SEQ){
    float a = 0.f;
    for (int e = 0; e < DM; e++) a += b2f(Xs[tid*XST+e])*sOv[e];
    a *= 0.08838834764831845f;   // 1/sqrt(128)
    out[(size_t)item*SEQ + tid] = (neighf[tid] > 0.5f) ? (1.f/(1.f+__expf(-a))) : 0.f;
  }
}

extern "C" void kernel_launch(void* const* d_in, const int* in_sizes, int n_in,
                              void* d_out, int out_size, void* d_ws, size_t ws_size,
                              hipStream_t stream)
{
  const float* agent_infos = (const float*)d_in[0];
  const int*   nmask       = (const int*)  d_in[1];
  const int*   pmask       = (const int*)  d_in[2];
  const float* W_emb = (const float*)d_in[4];
  const float* b_emb = (const float*)d_in[5];
  const float* Wq    = (const float*)d_in[6];
  const float* Wk    = (const float*)d_in[7];
  const float* Wv    = (const float*)d_in[8];
  const float* Wo    = (const float*)d_in[9];
  const float* ln1g  = (const float*)d_in[10];
  const float* ln1b  = (const float*)d_in[11];
  const float* W1    = (const float*)d_in[12];
  const float* b1    = (const float*)d_in[13];
  const float* W2    = (const float*)d_in[14];
  const float* b2    = (const float*)d_in[15];
  const float* ln2g  = (const float*)d_in[16];
  const float* ln2b  = (const float*)d_in[17];
  const float* Uq    = (const float*)d_in[18];
  const float* Uk    = (const float*)d_in[19];
  const float* Uv    = (const float*)d_in[20];
  const float* Uo    = (const float*)d_in[21];
  const float* ln3g  = (const float*)d_in[22];
  const float* ln3b  = (const float*)d_in[23];
  const float* W3    = (const float*)d_in[24];
  const float* b3    = (const float*)d_in[25];
  const float* W4    = (const float*)d_in[26];
  const float* b4    = (const float*)d_in[27];
  const float* ln4g  = (const float*)d_in[28];
  const float* ln4b  = (const float*)d_in[29];
  const float* Wgq   = (const float*)d_in[30];
  const float* Wgk   = (const float*)d_in[31];

  float* out = (float*)d_out;
  u16*   wts = (u16*)d_ws;   // 229376 bf16 = 458752 B

  prep_all<<<896, 256, 0, stream>>>(Wq, Wk, Wv, Wo, Uk, Uv, W1, W2, wts);
  init_avg<<<16, 256, 0, stream>>>(out);
  vicsek_fused<<<ITEMS, 256, 0, stream>>>(
      agent_infos, nmask, pmask, wts, W_emb, b_emb,
      ln1g, ln1b, b1, b2, ln2g, ln2b, Uq, Uo, ln3g, ln3b,
      W3, b3, W4, b4, ln4g, ln4b, Wgq, Wgk, out);
}

// Round 3
// 652.677 us; speedup vs baseline: 2.9416x; 1.9019x over previous
//
#include <hip/hip_runtime.h>
#include <hip/hip_bf16.h>
#include <math.h>

#define ITEMS 2048
#define SEQ   64
#define DM    128
#define DFF   512
#define ATT_OFF 131072

typedef unsigned short u16;
typedef __attribute__((ext_vector_type(4))) unsigned short ushort4v;
typedef __attribute__((ext_vector_type(8))) short short8v;
typedef __attribute__((ext_vector_type(4))) float float4v;

#define MFMA16(a,b,c) __builtin_amdgcn_mfma_f32_16x16x32_bf16(a,b,c,0,0,0)

// strides in u16 elements
#define XST 136   // 272B = 17*16  -> 16B aligned, 2-way banks
#define OST 136
#define QST 56    // 112B = 7*16   -> aligned, 2-way
#define PST 76    // scalar-only
#define VST 72    // 144B = 9*16   -> aligned, 2-way

// arena offsets (bytes)
#define XS_B   0          // u16 [64][136] = 17408
#define OB_B   17408      // u16 [64][136] = 17408 (attn-O, FFN hidden, tail scalars)
#define QH_B   34816      // u16 [64][56]  = 7168
#define KH_B   41984      // u16 [64][56]  = 7168
#define VT_B   49152      // u16 [16][72]  = 2304
#define P_B    34816      // u16 [64][76]  = 9728 (alias over QH/KH)
// tail aliases over QH/KH region (all dead by then)
#define WALL_B 34816      // f32[1024]
#define SALL_B 38912      // f32[512]
#define PALL_B 40960      // f32[512]
#define TALL_B 43008      // f32[1024]
#define FF_B   38912      // f32[512]  (over SALL, dead)
#define W4P_B  40960      // f32[256]  (over PALL, dead)
// tail scalars in OB region (Bb dead at tail)
#define HC_B   17408
#define QV_B   17920
#define OV_B   18432
#define YV_B   18944
#define Y2_B   19456
#define GW_B   19968
// persistent tail of arena
#define NF_B   51456      // neighf f32[64]
#define PF_B   51712      // padf   f32[64]
#define CNT_B  51968
#define NA_B   51972
#define NB_B   51976      // uint64
#define ARENA_SZ 51984

__device__ __forceinline__ u16 f2b(float f){
  union { float f; unsigned u; } v; v.f = f;
  unsigned r = (v.u + 0x7fffu + ((v.u >> 16) & 1u)) >> 16;
  return (u16)r;
}
__device__ __forceinline__ float b2f(u16 h){
  union { unsigned u; float f; } v; v.u = ((unsigned)h) << 16;
  return v.f;
}
__device__ __forceinline__ float wsum(float v){
  #pragma unroll
  for (int off = 1; off < 64; off <<= 1) v += __shfl_xor(v, off);
  return v;
}
__device__ __forceinline__ void ln_vec(float* v, const float* g, const float* b, int lane){
  float v0 = v[lane], v1 = v[lane+64];
  float m  = wsum(v0+v1) * (1.f/128.f);
  float d0 = v0-m, d1 = v1-m;
  float var = wsum(d0*d0+d1*d1) * (1.f/128.f);
  float inv = rsqrtf(var + 1e-5f);
  v[lane]    = d0*inv*g[lane]    + b[lane];
  v[lane+64] = d1*inv*g[lane+64] + b[lane+64];
}

__global__ void prep_all(const float* __restrict__ Wq, const float* __restrict__ Wk,
                         const float* __restrict__ Wv, const float* __restrict__ Wo,
                         const float* __restrict__ Uk, const float* __restrict__ Uv,
                         const float* __restrict__ W1, const float* __restrict__ W2,
                         u16* __restrict__ wts){
  int idx = blockIdx.x*256 + threadIdx.x;
  if (idx >= 229376) return;
  if (idx < 98304){                       // six 128x128 -> WT[out][in]
    int wsel = idx >> 14, r = idx & 16383;
    const float* tab[6] = {Wq,Wk,Wv,Wo,Uk,Uv};
    int o = r >> 7, i = r & 127;
    wts[idx] = f2b(tab[wsel][i*128 + o]);
  } else if (idx < 163840){               // W1T [512][128]
    int r = idx - 98304;
    int o = r >> 7, i = r & 127;
    wts[idx] = f2b(W1[i*512 + o]);
  } else {                                // W2T [128][512]
    int r = idx - 163840;
    int o = r >> 9, i = r & 511;
    wts[idx] = f2b(W2[i*128 + o]);
  }
}

__global__ void init_avg(float* __restrict__ out){
  out[ATT_OFF + blockIdx.x*256 + threadIdx.x] = 0.f;   // 16 x 256 = 4096
}

__global__ __launch_bounds__(256, 3) void vicsek_fused(
    const float* __restrict__ agent_infos,
    const int*   __restrict__ nmask,
    const int*   __restrict__ pmask,
    const u16*   __restrict__ wts,
    const float* __restrict__ W_emb, const float* __restrict__ b_emb,
    const float* __restrict__ ln1g,  const float* __restrict__ ln1b,
    const float* __restrict__ b1,    const float* __restrict__ b2,
    const float* __restrict__ ln2g,  const float* __restrict__ ln2b,
    const float* __restrict__ Uq,    const float* __restrict__ Uo,
    const float* __restrict__ ln3g,  const float* __restrict__ ln3b,
    const float* __restrict__ W3,    const float* __restrict__ b3,
    const float* __restrict__ W4,    const float* __restrict__ b4,
    const float* __restrict__ ln4g,  const float* __restrict__ ln4b,
    const float* __restrict__ Wgq,   const float* __restrict__ Wgk,
    float* __restrict__ out)
{
  __shared__ __align__(16) char arena[ARENA_SZ];
  u16* Xs = (u16*)(arena + XS_B);
  u16* Ob = (u16*)(arena + OB_B);
  u16* Qh = (u16*)(arena + QH_B);
  u16* Kh = (u16*)(arena + KH_B);
  u16* VT = (u16*)(arena + VT_B);
  u16* Pl = (u16*)(arena + P_B);
  float* neighf = (float*)(arena + NF_B);
  float* padf   = (float*)(arena + PF_B);
  float* cnt_s  = (float*)(arena + CNT_B);
  float* na_s   = (float*)(arena + NA_B);
  unsigned long long* nb_s = (unsigned long long*)(arena + NB_B);

  const int item = blockIdx.x;
  const int tid  = threadIdx.x;
  const int lane = tid & 63;
  const int w    = tid >> 6;
  const int row0 = w*16;
  const int arow = lane & 15;
  const int akg  = lane >> 4;

  const u16* WqT = wts;          const u16* WkT = wts + 16384;
  const u16* WvT = wts + 32768;  const u16* WoT = wts + 49152;
  const u16* UkT = wts + 65536;  const u16* UvT = wts + 81920;
  const u16* W1T = wts + 98304;  const u16* W2T = wts + 163840;

  // ---- flags (wave-parallel) ----
  if (w == 0){
    int m = nmask[item*SEQ + lane];
    neighf[lane] = m ? 1.f : 0.f;
    padf[lane]   = m ? 0.f : 1.f;          // reference: pad = ~neigh
    float c = wsum(m ? 1.f : 0.f);
    unsigned long long bb = __ballot(m != 0);
    if (lane == 0){ cnt_s[0] = c; nb_s[0] = bb; }
  }
  if (w == 1){
    float na = wsum((float)pmask[(item>>6)*SEQ + lane]);
    if (lane == 0) na_s[0] = na;
  }

  // ---- Stage A: embed ----
  const float* src = agent_infos + (size_t)item*SEQ*6;
  for (int e = tid; e < SEQ*DM; e += 256){
    int r = e >> 7, c = e & 127;
    float a = b_emb[c];
    #pragma unroll
    for (int k = 0; k < 6; k++) a += src[r*6+k]*W_emb[k*DM+c];
    Xs[r*XST + c] = f2b(a);
  }
  __syncthreads();

  const unsigned long long nbits = nb_s[0];

  short8v aX[4];
  #pragma unroll
  for (int k = 0; k < 4; k++) aX[k] = *(const short8v*)(Xs + (row0+arow)*XST + k*32 + akg*8);

  // ---- Stage B: self-MHA, per head, full MFMA ----
  for (int h = 0; h < 8; h++){
    __syncthreads();                        // guard Q/K/P/VT reuse
    // re-zero k-pad cols 16..31 of Q,K (P aliases clobber them each head)
    for (int idx = tid; idx < 1024; idx += 256){
      int r = idx >> 4, c2 = idx & 15;
      Qh[r*QST + 16 + c2] = 0;
      Kh[r*QST + 16 + c2] = 0;
    }
    {   // QKV staging: Q,K normal (A=X, B=W^T); V^T swapped (A=WvT, B=X^T)
      const u16* wq = WqT + (h*16+arow)*128 + akg*8;
      const u16* wk = WkT + (h*16+arow)*128 + akg*8;
      const u16* wv = WvT + (h*16+arow)*128 + akg*8;
      float4v cq = {0,0,0,0}, ck = {0,0,0,0}, cv = {0,0,0,0};
      #pragma unroll
      for (int k = 0; k < 4; k++){
        short8v bqf = *(const short8v*)(wq + k*32);
        short8v bkf = *(const short8v*)(wk + k*32);
        short8v bvf = *(const short8v*)(wv + k*32);
        cq = MFMA16(aX[k], bqf, cq);
        ck = MFMA16(aX[k], bkf, ck);
        cv = MFMA16(bvf, aX[k], cv);        // V^T[d][key]
      }
      #pragma unroll
      for (int i = 0; i < 4; i++){
        Qh[(row0+akg*4+i)*QST + arow] = f2b(cq[i]);
        Kh[(row0+akg*4+i)*QST + arow] = f2b(ck[i]);
        VT[(akg*4+i)*VST + row0 + arow] = f2b(cv[i]);
      }
    }
    __syncthreads();
    // S^T = K @ Q^T (k zero-padded to 32). Lane's q = row0+arow.
    short8v bq = *(const short8v*)(Qh + (row0+arow)*QST + akg*8);
    float4v st[4];
    #pragma unroll
    for (int kb = 0; kb < 4; kb++){
      short8v akf = *(const short8v*)(Kh + (kb*16+arow)*QST + akg*8);
      float4v z = {0,0,0,0};
      st[kb] = MFMA16(akf, bq, z);
    }
    // masked softmax over 64 keys (16 in-lane, x4 lane-groups)
    bool qok = (nbits >> (row0+arow)) & 1ull;
    float pr[16]; float mx = -3.0e38f;
    #pragma unroll
    for (int kb = 0; kb < 4; kb++)
      #pragma unroll
      for (int i = 0; i < 4; i++){
        int key = kb*16 + akg*4 + i;
        float s = st[kb][i]*0.25f;
        if (!qok || !((nbits>>key)&1ull)) s = -1.0e9f;
        pr[kb*4+i] = s; mx = fmaxf(mx, s);
      }
    mx = fmaxf(mx, __shfl_xor(mx,16)); mx = fmaxf(mx, __shfl_xor(mx,32));
    float sum = 0.f;
    #pragma unroll
    for (int z = 0; z < 16; z++){ pr[z] = __expf(pr[z]-mx); sum += pr[z]; }
    sum += __shfl_xor(sum,16); sum += __shfl_xor(sum,32);
    float inv = 1.f/sum;
    #pragma unroll
    for (int kb = 0; kb < 4; kb++)
      #pragma unroll
      for (int i = 0; i < 4; i++)
        Pl[(kb*16+akg*4+i)*PST + row0 + arow] = f2b(pr[kb*4+i]*inv);
    // PV: O^T = V^T @ P^T  (k = keys, 2 chunks of 32)
    float4v ot = {0,0,0,0};
    #pragma unroll
    for (int c2 = 0; c2 < 2; c2++){
      short8v avf = *(const short8v*)(VT + arow*VST + c2*32 + akg*8);
      short8v bp;
      #pragma unroll
      for (int j = 0; j < 8; j++) bp[j] = (short)Pl[(c2*32+akg*8+j)*PST + row0 + arow];
      ot = MFMA16(avf, bp, ot);
    }
    ushort4v ov4;
    #pragma unroll
    for (int i = 0; i < 4; i++) ov4[i] = f2b(ot[i]);
    *(ushort4v*)(Ob + (row0+arow)*OST + h*16 + akg*4) = ov4;
  }

  // ---- Wo projection + residual + LN1 (all own-wave rows, no sync needed) ----
  {
    float4v accW[8];
    #pragma unroll
    for (int t = 0; t < 8; t++)
      #pragma unroll
      for (int i = 0; i < 4; i++)
        accW[t][i] = b2f(Xs[(row0+akg*4+i)*XST + t*16 + arow]);
    short8v aO[4];
    #pragma unroll
    for (int k = 0; k < 4; k++) aO[k] = *(const short8v*)(Ob + (row0+arow)*OST + k*32 + akg*8);
    #pragma unroll
    for (int k = 0; k < 4; k++)
      #pragma unroll
      for (int t = 0; t < 8; t++)
        accW[t] = MFMA16(aO[k], *(const short8v*)(WoT + (t*16+arow)*128 + k*32 + akg*8), accW[t]);
    // LN1 in-register
    float g8[8], bb8[8];
    #pragma unroll
    for (int t = 0; t < 8; t++){ g8[t] = ln1g[t*16+arow]; bb8[t] = ln1b[t*16+arow]; }
    #pragma unroll
    for (int i = 0; i < 4; i++){
      float sm = 0.f;
      #pragma unroll
      for (int t = 0; t < 8; t++) sm += accW[t][i];
      sm += __shfl_xor(sm,1); sm += __shfl_xor(sm,2); sm += __shfl_xor(sm,4); sm += __shfl_xor(sm,8);
      float mean = sm*(1.f/128.f);
      float vs = 0.f;
      #pragma unroll
      for (int t = 0; t < 8; t++){ float d = accW[t][i]-mean; vs += d*d; }
      vs += __shfl_xor(vs,1); vs += __shfl_xor(vs,2); vs += __shfl_xor(vs,4); vs += __shfl_xor(vs,8);
      float inv = rsqrtf(vs*(1.f/128.f) + 1e-5f);
      #pragma unroll
      for (int t = 0; t < 8; t++)
        Xs[(row0+akg*4+i)*XST + t*16 + arow] = f2b((accW[t][i]-mean)*inv*g8[t] + bb8[t]);
    }
  }
  #pragma unroll
  for (int k = 0; k < 4; k++) aX[k] = *(const short8v*)(Xs + (row0+arow)*XST + k*32 + akg*8);

  // ---- Stage C: FFN, 4 hidden chunks of 128, all own-wave rows ----
  {
    float4v accY[8];
    #pragma unroll
    for (int t = 0; t < 8; t++){
      float bb = b2[t*16 + arow];
      #pragma unroll
      for (int i = 0; i < 4; i++)
        accY[t][i] = bb + b2f(Xs[(row0+akg*4+i)*XST + t*16 + arow]);
    }
    for (int c = 0; c < 4; c++){
      #pragma unroll
      for (int t = 0; t < 8; t++){
        float bb = b1[c*128 + t*16 + arow];
        float4v acc = {bb,bb,bb,bb};
        #pragma unroll
        for (int k = 0; k < 4; k++)
          acc = MFMA16(aX[k], *(const short8v*)(W1T + (c*128+t*16+arow)*128 + k*32 + akg*8), acc);
        #pragma unroll
        for (int i = 0; i < 4; i++)
          Ob[(row0+akg*4+i)*OST + t*16 + arow] = f2b(fmaxf(acc[i], 0.f));
      }
      #pragma unroll
      for (int k = 0; k < 4; k++){
        short8v aH = *(const short8v*)(Ob + (row0+arow)*OST + k*32 + akg*8);
        #pragma unroll
        for (int t = 0; t < 8; t++)
          accY[t] = MFMA16(aH, *(const short8v*)(W2T + (t*16+arow)*512 + c*128 + k*32 + akg*8), accY[t]);
      }
    }
    // LN2 in-register
    float g8[8], bb8[8];
    #pragma unroll
    for (int t = 0; t < 8; t++){ g8[t] = ln2g[t*16+arow]; bb8[t] = ln2b[t*16+arow]; }
    #pragma unroll
    for (int i = 0; i < 4; i++){
      float sm = 0.f;
      #pragma unroll
      for (int t = 0; t < 8; t++) sm += accY[t][i];
      sm += __shfl_xor(sm,1); sm += __shfl_xor(sm,2); sm += __shfl_xor(sm,4); sm += __shfl_xor(sm,8);
      float mean = sm*(1.f/128.f);
      float vs = 0.f;
      #pragma unroll
      for (int t = 0; t < 8; t++){ float d = accY[t][i]-mean; vs += d*d; }
      vs += __shfl_xor(vs,1); vs += __shfl_xor(vs,2); vs += __shfl_xor(vs,4); vs += __shfl_xor(vs,8);
      float inv = rsqrtf(vs*(1.f/128.f) + 1e-5f);
      #pragma unroll
      for (int t = 0; t < 8; t++)
        Xs[(row0+akg*4+i)*XST + t*16 + arow] = f2b((accY[t][i]-mean)*inv*g8[t] + bb8[t]);
    }
  }
  __syncthreads();   // Xs final; tail reads all rows

  // ---- tail pointers ----
  float* hc   = (float*)(arena + HC_B);
  float* qv   = (float*)(arena + QV_B);
  float* ov   = (float*)(arena + OV_B);
  float* yv   = (float*)(arena + YV_B);
  float* y2   = (float*)(arena + Y2_B);
  float* gw   = (float*)(arena + GW_B);
  float* wall = (float*)(arena + WALL_B);
  float* sall = (float*)(arena + SALL_B);
  float* pall = (float*)(arena + PALL_B);
  float* tall = (float*)(arena + TALL_B);
  float* ff   = (float*)(arena + FF_B);
  float* w4p  = (float*)(arena + W4P_B);

  // ---- Stage D: h_c + global average ----
  if (tid < DM){
    float a = 0.f;
    for (int r = 0; r < SEQ; r++) a += b2f(Xs[r*XST + tid]) * padf[r];
    a /= cnt_s[0];
    hc[tid] = a;
    atomicAdd(&out[ATT_OFF + (item>>6)*DM + tid], a/na_s[0]);
  }
  __syncthreads();

  // ---- Stage E: cross-attention, batched over heads ----
  if (tid < DM){
    float a = 0.f;
    #pragma unroll 8
    for (int e = 0; e < DM; e++) a += hc[e]*Uq[e*DM + tid];
    qv[tid] = a;
  }
  __syncthreads();
  if (tid < DM){   // w_all[h][e] = sum_d UkT[h*16+d][e] * q[h*16+d]
    #pragma unroll
    for (int h = 0; h < 8; h++){
      float a = 0.f;
      #pragma unroll
      for (int d = 0; d < 16; d++) a += b2f(UkT[(h*16+d)*128 + tid]) * qv[h*16+d];
      wall[h*128 + tid] = a;
    }
  }
  __syncthreads();
  for (int idx = tid; idx < 512; idx += 256){   // s_all[h][j] = x_j . w_h (scaled)
    int h = idx >> 6, j = idx & 63;
    const short8v* xr = (const short8v*)(Xs + j*XST);
    const float* wv_ = wall + h*128;
    float a = 0.f;
    #pragma unroll
    for (int c8 = 0; c8 < 16; c8++){
      short8v v = xr[c8];
      #pragma unroll
      for (int q = 0; q < 8; q++) a += b2f((u16)v[q]) * wv_[c8*8+q];
    }
    sall[idx] = a*0.25f;
  }
  __syncthreads();
  for (int hh = w; hh < 8; hh += 4){            // softmax per head (key mask only)
    float s = sall[hh*64 + lane];
    if (!((nbits>>lane)&1ull)) s = -1.0e9f;
    float mxx = s;
    #pragma unroll
    for (int off = 1; off < 64; off <<= 1) mxx = fmaxf(mxx, __shfl_xor(mxx, off));
    float p = __expf(s - mxx);
    float su = wsum(p);
    pall[hh*64 + lane] = p/su;
  }
  __syncthreads();
  for (int idx = tid; idx < 1024; idx += 256){  // t_all[h][c] = p_h . X[:,c]
    int h = idx >> 7, c = idx & 127;
    float a = 0.f;
    for (int j = 0; j < SEQ; j++) a += pall[h*64+j] * b2f(Xs[j*XST + c]);
    tall[idx] = a;
  }
  __syncthreads();
  if (tid < DM){   // o[tid] = t_h . UvT[tid]  (h = tid>>4)
    const short8v* ur = (const short8v*)(UvT + tid*128);
    const float* th = tall + (tid>>4)*128;
    float a = 0.f;
    #pragma unroll
    for (int c8 = 0; c8 < 16; c8++){
      short8v v = ur[c8];
      #pragma unroll
      for (int q = 0; q < 8; q++) a += b2f((u16)v[q]) * th[c8*8+q];
    }
    ov[tid] = a;
  }
  __syncthreads();
  if (tid < DM){   // y = hc + o @ Uo
    float a = 0.f;
    #pragma unroll 8
    for (int e = 0; e < DM; e++) a += ov[e]*Uo[e*DM + tid];
    yv[tid] = hc[tid] + a;
  }
  __syncthreads();
  if (w == 0) ln_vec(yv, ln3g, ln3b, lane);
  __syncthreads();

  // ---- Stage F: 1-row FFN + LN4 ----
  for (int j = tid; j < DFF; j += 256){
    float a = b3[j];
    #pragma unroll 8
    for (int e = 0; e < DM; e++) a += yv[e]*W3[e*DFF + j];
    ff[j] = fmaxf(a, 0.f);
  }
  __syncthreads();
  {
    int o = tid & 127, half = tid >> 7;
    float a = 0.f;
    #pragma unroll 8
    for (int j = half*256; j < half*256+256; j++) a += ff[j]*W4[j*DM + o];
    w4p[tid] = a;
  }
  __syncthreads();
  if (tid < DM) y2[tid] = b4[tid] + yv[tid] + w4p[tid] + w4p[tid+128];
  __syncthreads();
  if (w == 0) ln_vec(y2, ln4g, ln4b, lane);
  __syncthreads();

  // ---- Stage G: gating ----
  if (tid < DM){
    float a = 0.f;
    #pragma unroll 8
    for (int e = 0; e < DM; e++) a += y2[e]*Wgq[e*DM + tid];
    qv[tid] = a;    // gq (qv dead)
  }
  __syncthreads();
  if (tid < DM){
    const float4* wr = (const float4*)(Wgk + tid*DM);
    float a = 0.f;
    #pragma unroll
    for (int c4 = 0; c4 < 32; c4++){
      float4 v = wr[c4];
      a += v.x*qv[c4*4] + v.y*qv[c4*4+1] + v.z*qv[c4*4+2] + v.w*qv[c4*4+3];
    }
    gw[tid] = a;
  }
  __syncthreads();
  if (tid < SEQ){
    const short8v* xr = (const short8v*)(Xs + tid*XST);
    float a = 0.f;
    #pragma unroll
    for (int c8 = 0; c8 < 16; c8++){
      short8v v = xr[c8];
      #pragma unroll
      for (int q = 0; q < 8; q++) a += b2f((u16)v[q]) * gw[c8*8+q];
    }
    a *= 0.08838834764831845f;   // 1/sqrt(128)
    out[(size_t)item*SEQ + tid] = ((nbits>>tid)&1ull) ? (1.f/(1.f+__expf(-a))) : 0.f;
  }
}

extern "C" void kernel_launch(void* const* d_in, const int* in_sizes, int n_in,
                              void* d_out, int out_size, void* d_ws, size_t ws_size,
                              hipStream_t stream)
{
  const float* agent_infos = (const float*)d_in[0];
  const int*   nmask       = (const int*)  d_in[1];
  const int*   pmask       = (const int*)  d_in[2];
  const float* W_emb = (const float*)d_in[4];
  const float* b_emb = (const float*)d_in[5];
  const float* Wq    = (const float*)d_in[6];
  const float* Wk    = (const float*)d_in[7];
  const float* Wv    = (const float*)d_in[8];
  const float* Wo    = (const float*)d_in[9];
  const float* ln1g  = (const float*)d_in[10];
  const float* ln1b  = (const float*)d_in[11];
  const float* W1    = (const float*)d_in[12];
  const float* b1    = (const float*)d_in[13];
  const float* W2    = (const float*)d_in[14];
  const float* b2    = (const float*)d_in[15];
  const float* ln2g  = (const float*)d_in[16];
  const float* ln2b  = (const float*)d_in[17];
  const float* Uq    = (const float*)d_in[18];
  const float* Uk    = (const float*)d_in[19];
  const float* Uv    = (const float*)d_in[20];
  const float* Uo    = (const float*)d_in[21];
  const float* ln3g  = (const float*)d_in[22];
  const float* ln3b  = (const float*)d_in[23];
  const float* W3    = (const float*)d_in[24];
  const float* b3    = (const float*)d_in[25];
  const float* W4    = (const float*)d_in[26];
  const float* b4    = (const float*)d_in[27];
  const float* ln4g  = (const float*)d_in[28];
  const float* ln4b  = (const float*)d_in[29];
  const float* Wgq   = (const float*)d_in[30];
  const float* Wgk   = (const float*)d_in[31];

  float* out = (float*)d_out;
  u16*   wts = (u16*)d_ws;   // 229376 bf16 = 458752 B

  prep_all<<<896, 256, 0, stream>>>(Wq, Wk, Wv, Wo, Uk, Uv, W1, W2, wts);
  init_avg<<<16, 256, 0, stream>>>(out);
  vicsek_fused<<<ITEMS, 256, 0, stream>>>(
      agent_infos, nmask, pmask, wts, W_emb, b_emb,
      ln1g, ln1b, b1, b2, ln2g, ln2b, Uq, Uo, ln3g, ln3b,
      W3, b3, W4, b4, ln4g, ln4b, Wgq, Wgk, out);
}

// Round 4
// 636.056 us; speedup vs baseline: 3.0185x; 1.0261x over previous
//
#include <hip/hip_runtime.h>
#include <hip/hip_bf16.h>
#include <math.h>

#define ITEMS 2048
#define SEQ   64
#define DM    128
#define DFF   512
#define ATT_OFF 131072

typedef unsigned short u16;
typedef __attribute__((ext_vector_type(4))) unsigned short ushort4v;
typedef __attribute__((ext_vector_type(8))) short short8v;
typedef __attribute__((ext_vector_type(4))) float float4v;

#define MFMA16(a,b,c) __builtin_amdgcn_mfma_f32_16x16x32_bf16(a,b,c,0,0,0)

// strides in u16 elements
#define XST 136   // 272B rows: 16B aligned, 2-way banks (free)
#define VST 72    // V^T rows
#define PST 76    // P rows

// arena byte offsets
#define XS_B   0          // u16[64][136] 17408  X -> O -> LN1 -> LN2 (final X)
#define QS_B   17408      // u16[64][136] 17408  Q all heads; FFN hidden alias
#define KS_B   34816      // u16[64][136] 17408  K all heads; tail scalars alias
#define VT_B   52224      // u16[128][72] 18432  V^T all heads; tail arrays alias
#define PL_B   70656      // u16[64][76]  9728   P (same-wave use only)
#define ZB_B   80384      // u16[8] zero frag (16B)
#define PF_B   80400      // f32[64] padf
#define CNT_B  80656
#define NA_B   80660
#define NB_B   80664      // u64
#define ARENA_SZ 80672

// tail aliases
#define HC_B   (KS_B+0)
#define QV_B   (KS_B+512)
#define OV_B   (KS_B+1024)
#define YV_B   (KS_B+1536)
#define Y2_B   (KS_B+2048)
#define GW_B   (KS_B+2560)
#define WALL_B (VT_B+0)      // f32[1024]
#define SALL_B (VT_B+4096)   // f32[512]
#define PALL_B (VT_B+6144)   // f32[512]
#define TALL_B (VT_B+8192)   // f32[1024]
#define FF_B   (VT_B+12288)  // f32[512]
#define W4P_B  (VT_B+14336)  // f32[256]

// ws layout (u16 elements)
#define WQ_O   0
#define WK_O   16384
#define WV_O   32768
#define WO_O   49152
#define UK_O   65536
#define UV_O   81920
#define W1_O   98304     // [512][128]
#define W2_O   163840    // [128][512]
#define UQ_O   229376    // [128][128] T
#define UO_O   245760
#define WGQ_O  262144
#define WGK_O  278528    // row-major copy
#define W3_O   294912    // [512][128] T
#define W4_O   360448    // [128][512] T
#define WS_TOT 425984

__device__ __forceinline__ u16 f2b(float f){
  union { float f; unsigned u; } v; v.f = f;
  unsigned r = (v.u + 0x7fffu + ((v.u >> 16) & 1u)) >> 16;
  return (u16)r;
}
__device__ __forceinline__ float b2f(u16 h){
  union { unsigned u; float f; } v; v.u = ((unsigned)h) << 16;
  return v.f;
}
__device__ __forceinline__ float wsum(float v){
  #pragma unroll
  for (int off = 1; off < 64; off <<= 1) v += __shfl_xor(v, off);
  return v;
}
__device__ __forceinline__ void ln_vec(float* v, const float* g, const float* b, int lane){
  float v0 = v[lane], v1 = v[lane+64];
  float m  = wsum(v0+v1) * (1.f/128.f);
  float d0 = v0-m, d1 = v1-m;
  float var = wsum(d0*d0+d1*d1) * (1.f/128.f);
  float inv = rsqrtf(var + 1e-5f);
  v[lane]    = d0*inv*g[lane]    + b[lane];
  v[lane+64] = d1*inv*g[lane+64] + b[lane+64];
}
// dot of 128-bf16 row (16 x b128) with f32 LDS vector
__device__ __forceinline__ float dot128(const u16* __restrict__ wrow, const float* __restrict__ x){
  const short8v* wr = (const short8v*)wrow;
  float a = 0.f;
  #pragma unroll
  for (int c8 = 0; c8 < 16; c8++){
    short8v v = wr[c8];
    #pragma unroll
    for (int q = 0; q < 8; q++) a += b2f((u16)v[q]) * x[c8*8+q];
  }
  return a;
}

__global__ void prep_all(const float* __restrict__ Wq, const float* __restrict__ Wk,
                         const float* __restrict__ Wv, const float* __restrict__ Wo,
                         const float* __restrict__ Uk, const float* __restrict__ Uv,
                         const float* __restrict__ W1, const float* __restrict__ W2,
                         const float* __restrict__ Uq, const float* __restrict__ Uo,
                         const float* __restrict__ Wgq, const float* __restrict__ Wgk,
                         const float* __restrict__ W3, const float* __restrict__ W4,
                         u16* __restrict__ wts){
  int idx = blockIdx.x*256 + threadIdx.x;
  if (idx >= WS_TOT) return;
  float v;
  if (idx < 98304){                       // six 128x128 -> T[out][in]
    int wsel = idx >> 14, r = idx & 16383;
    const float* tab[6] = {Wq,Wk,Wv,Wo,Uk,Uv};
    int o = r >> 7, i = r & 127;
    v = tab[wsel][i*128 + o];
  } else if (idx < W2_O){                 // W1T [512][128]
    int r = idx - W1_O; int o = r >> 7, i = r & 127;
    v = W1[i*512 + o];
  } else if (idx < UQ_O){                 // W2T [128][512]
    int r = idx - W2_O; int o = r >> 9, i = r & 511;
    v = W2[i*128 + o];
  } else if (idx < UO_O){
    int r = idx - UQ_O; int o = r >> 7, i = r & 127;
    v = Uq[i*128 + o];
  } else if (idx < WGQ_O){
    int r = idx - UO_O; int o = r >> 7, i = r & 127;
    v = Uo[i*128 + o];
  } else if (idx < WGK_O){
    int r = idx - WGQ_O; int o = r >> 7, i = r & 127;
    v = Wgq[i*128 + o];
  } else if (idx < W3_O){
    v = Wgk[idx - WGK_O];                 // already [out][in]
  } else if (idx < W4_O){
    int r = idx - W3_O; int j = r >> 7, e = r & 127;
    v = W3[e*512 + j];
  } else {
    int r = idx - W4_O; int o = r >> 9, j = r & 511;
    v = W4[j*128 + o];
  }
  wts[idx] = f2b(v);
}

__global__ void init_avg(float* __restrict__ out){
  out[ATT_OFF + blockIdx.x*256 + threadIdx.x] = 0.f;   // 16 x 256
}

__global__ __launch_bounds__(256, 2) void vicsek_fused(
    const float* __restrict__ agent_infos,
    const int*   __restrict__ nmask,
    const int*   __restrict__ pmask,
    const u16*   __restrict__ wts,
    const float* __restrict__ W_emb, const float* __restrict__ b_emb,
    const float* __restrict__ ln1g,  const float* __restrict__ ln1b,
    const float* __restrict__ b1,    const float* __restrict__ b2,
    const float* __restrict__ ln2g,  const float* __restrict__ ln2b,
    const float* __restrict__ ln3g,  const float* __restrict__ ln3b,
    const float* __restrict__ b3,    const float* __restrict__ b4,
    const float* __restrict__ ln4g,  const float* __restrict__ ln4b,
    float* __restrict__ out)
{
  __shared__ __align__(16) char arena[ARENA_SZ];
  u16* Xs = (u16*)(arena + XS_B);
  u16* Qs = (u16*)(arena + QS_B);
  u16* Ks = (u16*)(arena + KS_B);
  u16* VT = (u16*)(arena + VT_B);
  u16* Pl = (u16*)(arena + PL_B);
  u16* zb = (u16*)(arena + ZB_B);
  float* padf  = (float*)(arena + PF_B);
  float* cnt_s = (float*)(arena + CNT_B);
  float* na_s  = (float*)(arena + NA_B);
  unsigned long long* nb_s = (unsigned long long*)(arena + NB_B);

  const int item = blockIdx.x;
  const int tid  = threadIdx.x;
  const int lane = tid & 63;
  const int w    = tid >> 6;
  const int row0 = w*16;
  const int arow = lane & 15;
  const int akg  = lane >> 4;

  const u16* WqT = wts + WQ_O;  const u16* WkT = wts + WK_O;
  const u16* WvT = wts + WV_O;  const u16* WoT = wts + WO_O;
  const u16* UkT = wts + UK_O;  const u16* UvT = wts + UV_O;
  const u16* W1T = wts + W1_O;  const u16* W2T = wts + W2_O;
  const u16* UqT = wts + UQ_O;  const u16* UoT = wts + UO_O;
  const u16* WgqT = wts + WGQ_O; const u16* WgkB = wts + WGK_O;
  const u16* W3T = wts + W3_O;  const u16* W4T = wts + W4_O;

  // ---- flags ----
  if (w == 0){
    int m = nmask[item*SEQ + lane];
    padf[lane] = m ? 0.f : 1.f;            // reference: pad = ~neigh
    float c = wsum(m ? 1.f : 0.f);
    unsigned long long bb = __ballot(m != 0);
    if (lane == 0){ cnt_s[0] = c; nb_s[0] = bb; }
  }
  if (w == 1){
    float na = wsum((float)pmask[(item>>6)*SEQ + lane]);
    if (lane == 0) na_s[0] = na;
  }
  if (tid < 8) zb[tid] = 0;

  // ---- Stage A: embed ----
  const float* src = agent_infos + (size_t)item*SEQ*6;
  for (int e = tid; e < SEQ*DM; e += 256){
    int r = e >> 7, c = e & 127;
    float a = b_emb[c];
    #pragma unroll
    for (int k = 0; k < 6; k++) a += src[r*6+k]*W_emb[k*DM+c];
    Xs[r*XST + c] = f2b(a);
  }
  __syncthreads();

  const unsigned long long nbits = nb_s[0];

  short8v aX[4];
  #pragma unroll
  for (int k = 0; k < 4; k++) aX[k] = *(const short8v*)(Xs + (row0+arow)*XST + k*32 + akg*8);

  // ---- Stage B0: stage Q,K (normal) and V^T (swapped) for ALL heads, once ----
  for (int t = 0; t < 8; t++){
    const u16* wq = WqT + (t*16+arow)*128 + akg*8;
    const u16* wk = WkT + (t*16+arow)*128 + akg*8;
    const u16* wv = WvT + (t*16+arow)*128 + akg*8;
    float4v cq = {0,0,0,0}, ck = {0,0,0,0}, cv = {0,0,0,0};
    #pragma unroll
    for (int k = 0; k < 4; k++){
      cq = MFMA16(aX[k], *(const short8v*)(wq + k*32), cq);
      ck = MFMA16(aX[k], *(const short8v*)(wk + k*32), ck);
      cv = MFMA16(*(const short8v*)(wv + k*32), aX[k], cv);   // V^T[d][key]
    }
    #pragma unroll
    for (int i = 0; i < 4; i++){
      Qs[(row0+akg*4+i)*XST + t*16+arow] = f2b(cq[i]);
      Ks[(row0+akg*4+i)*XST + t*16+arow] = f2b(ck[i]);
      VT[(t*16+akg*4+i)*VST + row0+arow] = f2b(cv[i]);
    }
  }
  // residual preload (Xs will be overwritten by attention O)
  float4v accW[8];
  #pragma unroll
  for (int t = 0; t < 8; t++)
    #pragma unroll
    for (int i = 0; i < 4; i++)
      accW[t][i] = b2f(Xs[(row0+akg*4+i)*XST + t*16 + arow]);
  __syncthreads();

  // ---- Stage B1: head loop — NO barriers ----
  for (int h = 0; h < 8; h++){
    // Q fragment (B operand), k 16..31 -> zero slot
    const u16* qp = (akg < 2) ? (Qs + (row0+arow)*XST + h*16 + akg*8) : zb;
    short8v bq = *(const short8v*)qp;
    float4v st[4];
    #pragma unroll
    for (int kb = 0; kb < 4; kb++){
      const u16* kp = (akg < 2) ? (Ks + (kb*16+arow)*XST + h*16 + akg*8) : zb;
      float4v z = {0,0,0,0};
      st[kb] = MFMA16(*(const short8v*)kp, bq, z);
    }
    // masked softmax over 64 keys (16 in-lane x 4 lane-groups)
    bool qok = (nbits >> (row0+arow)) & 1ull;
    float pr[16]; float mx = -3.0e38f;
    #pragma unroll
    for (int kb = 0; kb < 4; kb++)
      #pragma unroll
      for (int i = 0; i < 4; i++){
        int key = kb*16 + akg*4 + i;
        float s = st[kb][i]*0.25f;
        if (!qok || !((nbits>>key)&1ull)) s = -1.0e9f;
        pr[kb*4+i] = s; mx = fmaxf(mx, s);
      }
    mx = fmaxf(mx, __shfl_xor(mx,16)); mx = fmaxf(mx, __shfl_xor(mx,32));
    float sum = 0.f;
    #pragma unroll
    for (int z = 0; z < 16; z++){ pr[z] = __expf(pr[z]-mx); sum += pr[z]; }
    sum += __shfl_xor(sum,16); sum += __shfl_xor(sum,32);
    float inv = 1.f/sum;
    #pragma unroll
    for (int kb = 0; kb < 4; kb++)
      #pragma unroll
      for (int i = 0; i < 4; i++)
        Pl[(kb*16+akg*4+i)*PST + row0+arow] = f2b(pr[kb*4+i]*inv);
    // PV: O^T = V^T @ P^T (same-wave LDS, in-order DS pipe, no barrier)
    float4v ot = {0,0,0,0};
    #pragma unroll
    for (int c2 = 0; c2 < 2; c2++){
      short8v av = *(const short8v*)(VT + (h*16+arow)*VST + c2*32 + akg*8);
      short8v bp;
      #pragma unroll
      for (int j = 0; j < 8; j++) bp[j] = (short)Pl[(c2*32+akg*8+j)*PST + row0+arow];
      ot = MFMA16(av, bp, ot);
    }
    ushort4v ov4;
    #pragma unroll
    for (int i = 0; i < 4; i++) ov4[i] = f2b(ot[i]);
    *(ushort4v*)(Xs + (row0+arow)*XST + h*16 + akg*4) = ov4;   // O overwrites X
  }

  // ---- Wo projection + residual + LN1 (own-wave rows only) ----
  {
    short8v aO[4];
    #pragma unroll
    for (int k = 0; k < 4; k++) aO[k] = *(const short8v*)(Xs + (row0+arow)*XST + k*32 + akg*8);
    #pragma unroll
    for (int k = 0; k < 4; k++)
      #pragma unroll
      for (int t = 0; t < 8; t++)
        accW[t] = MFMA16(aO[k], *(const short8v*)(WoT + (t*16+arow)*128 + k*32 + akg*8), accW[t]);
    float g8[8], bb8[8];
    #pragma unroll
    for (int t = 0; t < 8; t++){ g8[t] = ln1g[t*16+arow]; bb8[t] = ln1b[t*16+arow]; }
    #pragma unroll
    for (int i = 0; i < 4; i++){
      float sm = 0.f;
      #pragma unroll
      for (int t = 0; t < 8; t++) sm += accW[t][i];
      sm += __shfl_xor(sm,1); sm += __shfl_xor(sm,2); sm += __shfl_xor(sm,4); sm += __shfl_xor(sm,8);
      float mean = sm*(1.f/128.f);
      float vs = 0.f;
      #pragma unroll
      for (int t = 0; t < 8; t++){ float d = accW[t][i]-mean; vs += d*d; }
      vs += __shfl_xor(vs,1); vs += __shfl_xor(vs,2); vs += __shfl_xor(vs,4); vs += __shfl_xor(vs,8);
      float inv = rsqrtf(vs*(1.f/128.f) + 1e-5f);
      #pragma unroll
      for (int t = 0; t < 8; t++)
        Xs[(row0+akg*4+i)*XST + t*16 + arow] = f2b((accW[t][i]-mean)*inv*g8[t] + bb8[t]);
    }
  }
  #pragma unroll
  for (int k = 0; k < 4; k++) aX[k] = *(const short8v*)(Xs + (row0+arow)*XST + k*32 + akg*8);

  // ---- Stage C: FFN, hidden chunks in Qs alias (own-wave rows, no barriers) ----
  {
    u16* Hb = Qs;
    float4v accY[8];
    #pragma unroll
    for (int t = 0; t < 8; t++){
      float bb = b2[t*16 + arow];
      #pragma unroll
      for (int i = 0; i < 4; i++)
        accY[t][i] = bb + b2f(Xs[(row0+akg*4+i)*XST + t*16 + arow]);
    }
    for (int c = 0; c < 4; c++){
      #pragma unroll
      for (int t = 0; t < 8; t++){
        float bb = b1[c*128 + t*16 + arow];
        float4v acc = {bb,bb,bb,bb};
        #pragma unroll
        for (int k = 0; k < 4; k++)
          acc = MFMA16(aX[k], *(const short8v*)(W1T + (c*128+t*16+arow)*128 + k*32 + akg*8), acc);
        #pragma unroll
        for (int i = 0; i < 4; i++)
          Hb[(row0+akg*4+i)*XST + t*16 + arow] = f2b(fmaxf(acc[i], 0.f));
      }
      #pragma unroll
      for (int k = 0; k < 4; k++){
        short8v aH = *(const short8v*)(Hb + (row0+arow)*XST + k*32 + akg*8);
        #pragma unroll
        for (int t = 0; t < 8; t++)
          accY[t] = MFMA16(aH, *(const short8v*)(W2T + (t*16+arow)*512 + c*128 + k*32 + akg*8), accY[t]);
      }
    }
    float g8[8], bb8[8];
    #pragma unroll
    for (int t = 0; t < 8; t++){ g8[t] = ln2g[t*16+arow]; bb8[t] = ln2b[t*16+arow]; }
    #pragma unroll
    for (int i = 0; i < 4; i++){
      float sm = 0.f;
      #pragma unroll
      for (int t = 0; t < 8; t++) sm += accY[t][i];
      sm += __shfl_xor(sm,1); sm += __shfl_xor(sm,2); sm += __shfl_xor(sm,4); sm += __shfl_xor(sm,8);
      float mean = sm*(1.f/128.f);
      float vs = 0.f;
      #pragma unroll
      for (int t = 0; t < 8; t++){ float d = accY[t][i]-mean; vs += d*d; }
      vs += __shfl_xor(vs,1); vs += __shfl_xor(vs,2); vs += __shfl_xor(vs,4); vs += __shfl_xor(vs,8);
      float inv = rsqrtf(vs*(1.f/128.f) + 1e-5f);
      #pragma unroll
      for (int t = 0; t < 8; t++)
        Xs[(row0+akg*4+i)*XST + t*16 + arow] = f2b((accY[t][i]-mean)*inv*g8[t] + bb8[t]);
    }
  }
  __syncthreads();   // Xs final; tail reads all rows; K/V regions become scratch

  float* hc   = (float*)(arena + HC_B);
  float* qv   = (float*)(arena + QV_B);
  float* ov   = (float*)(arena + OV_B);
  float* yv   = (float*)(arena + YV_B);
  float* y2   = (float*)(arena + Y2_B);
  float* gw   = (float*)(arena + GW_B);
  float* wall = (float*)(arena + WALL_B);
  float* sall = (float*)(arena + SALL_B);
  float* pall = (float*)(arena + PALL_B);
  float* tall = (float*)(arena + TALL_B);
  float* ff   = (float*)(arena + FF_B);
  float* w4p  = (float*)(arena + W4P_B);

  // ---- Stage D: h_c + global average ----
  if (tid < DM){
    float a = 0.f;
    #pragma unroll 8
    for (int r = 0; r < SEQ; r++) a += b2f(Xs[r*XST + tid]) * padf[r];
    a /= cnt_s[0];
    hc[tid] = a;
    atomicAdd(&out[ATT_OFF + (item>>6)*DM + tid], a/na_s[0]);
  }
  __syncthreads();

  // ---- Stage E: cross-attention (1 query), batched over heads ----
  if (tid < DM) qv[tid] = dot128(UqT + tid*128, hc);
  __syncthreads();
  if (tid < DM){   // wall[h][e] = sum_d UkT[h*16+d][e] * q[h*16+d]
    #pragma unroll
    for (int h = 0; h < 8; h++){
      float a = 0.f;
      #pragma unroll
      for (int d = 0; d < 16; d++) a += b2f(UkT[(h*16+d)*128 + tid]) * qv[h*16+d];
      wall[h*128 + tid] = a;
    }
  }
  __syncthreads();
  for (int idx = tid; idx < 512; idx += 256){   // sall[h][j] = x_j . w_h
    int h = idx >> 6, j = idx & 63;
    const short8v* xr = (const short8v*)(Xs + j*XST);
    const float* wv_ = wall + h*128;
    float a = 0.f;
    #pragma unroll
    for (int c8 = 0; c8 < 16; c8++){
      short8v v = xr[c8];
      #pragma unroll
      for (int q = 0; q < 8; q++) a += b2f((u16)v[q]) * wv_[c8*8+q];
    }
    sall[idx] = a*0.25f;
  }
  __syncthreads();
  for (int hh = w; hh < 8; hh += 4){            // per-head softmax (key mask)
    float s = sall[hh*64 + lane];
    if (!((nbits>>lane)&1ull)) s = -1.0e9f;
    float mxx = s;
    #pragma unroll
    for (int off = 1; off < 64; off <<= 1) mxx = fmaxf(mxx, __shfl_xor(mxx, off));
    float p = __expf(s - mxx);
    float su = wsum(p);
    pall[hh*64 + lane] = p/su;
  }
  __syncthreads();
  {   // tall[h][c] = p_h . X[:,c] — thread pairs, vectorized rows
    int task = tid >> 1, jh = tid & 1;          // task: h=task>>4, c8=task&15
    int h = task >> 4, c8 = task & 15;
    float acc8[8] = {0,0,0,0,0,0,0,0};
    #pragma unroll 4
    for (int jj = 0; jj < 32; jj++){
      int j = jh*32 + jj;
      short8v v = *(const short8v*)(Xs + j*XST + c8*8);
      float pj = pall[h*64 + j];
      #pragma unroll
      for (int q = 0; q < 8; q++) acc8[q] += pj * b2f((u16)v[q]);
    }
    #pragma unroll
    for (int q = 0; q < 8; q++) acc8[q] += __shfl_xor(acc8[q], 1);
    if (jh == 0){
      #pragma unroll
      for (int q = 0; q < 8; q++) tall[h*128 + c8*8 + q] = acc8[q];
    }
  }
  __syncthreads();
  if (tid < DM) ov[tid] = dot128(UvT + tid*128, tall + (tid>>4)*128);
  __syncthreads();
  if (tid < DM) yv[tid] = hc[tid] + dot128(UoT + tid*128, ov);
  __syncthreads();
  if (w == 0) ln_vec(yv, ln3g, ln3b, lane);
  __syncthreads();

  // ---- Stage F: 1-row FFN + LN4 ----
  for (int j = tid; j < DFF; j += 256)
    ff[j] = fmaxf(b3[j] + dot128(W3T + j*128, yv), 0.f);
  __syncthreads();
  {
    int o = tid & 127, half = tid >> 7;
    const short8v* wr = (const short8v*)(W4T + o*512 + half*256);
    const float* fh = ff + half*256;
    float a = 0.f;
    #pragma unroll
    for (int c8 = 0; c8 < 32; c8++){
      short8v v = wr[c8];
      #pragma unroll
      for (int q = 0; q < 8; q++) a += b2f((u16)v[q]) * fh[c8*8+q];
    }
    w4p[tid] = a;
  }
  __syncthreads();
  if (tid < DM) y2[tid] = b4[tid] + yv[tid] + w4p[tid] + w4p[tid+128];
  __syncthreads();
  if (w == 0) ln_vec(y2, ln4g, ln4b, lane);
  __syncthreads();

  // ---- Stage G: gating ----
  if (tid < DM) qv[tid] = dot128(WgqT + tid*128, y2);   // gq
  __syncthreads();
  if (tid < DM) gw[tid] = dot128(WgkB + tid*128, qv);   // w = Wg_k . gq
  __syncthreads();
  if (tid < SEQ){
    float a = dot128(Xs + tid*XST, gw) ;  // note: Xs row is bf16; gw f32
    a *= 0.08838834764831845f;            // 1/sqrt(128)
    out[(size_t)item*SEQ + tid] = ((nbits>>tid)&1ull) ? (1.f/(1.f+__expf(-a))) : 0.f;
  }
}

extern "C" void kernel_launch(void* const* d_in, const int* in_sizes, int n_in,
                              void* d_out, int out_size, void* d_ws, size_t ws_size,
                              hipStream_t stream)
{
  const float* agent_infos = (const float*)d_in[0];
  const int*   nmask       = (const int*)  d_in[1];
  const int*   pmask       = (const int*)  d_in[2];
  const float* W_emb = (const float*)d_in[4];
  const float* b_emb = (const float*)d_in[5];
  const float* Wq    = (const float*)d_in[6];
  const float* Wk    = (const float*)d_in[7];
  const float* Wv    = (const float*)d_in[8];
  const float* Wo    = (const float*)d_in[9];
  const float* ln1g  = (const float*)d_in[10];
  const float* ln1b  = (const float*)d_in[11];
  const float* W1    = (const float*)d_in[12];
  const float* b1    = (const float*)d_in[13];
  const float* W2    = (const float*)d_in[14];
  const float* b2    = (const float*)d_in[15];
  const float* ln2g  = (const float*)d_in[16];
  const float* ln2b  = (const float*)d_in[17];
  const float* Uq    = (const float*)d_in[18];
  const float* Uk    = (const float*)d_in[19];
  const float* Uv    = (const float*)d_in[20];
  const float* Uo    = (const float*)d_in[21];
  const float* ln3g  = (const float*)d_in[22];
  const float* ln3b  = (const float*)d_in[23];
  const float* W3    = (const float*)d_in[24];
  const float* b3    = (const float*)d_in[25];
  const float* W4    = (const float*)d_in[26];
  const float* b4    = (const float*)d_in[27];
  const float* ln4g  = (const float*)d_in[28];
  const float* ln4b  = (const float*)d_in[29];
  const float* Wgq   = (const float*)d_in[30];
  const float* Wgk   = (const float*)d_in[31];

  float* out = (float*)d_out;
  u16*   wts = (u16*)d_ws;   // 425984 u16 = 851968 B (< 1 MB proven ws budget)

  prep_all<<<(WS_TOT+255)/256, 256, 0, stream>>>(Wq, Wk, Wv, Wo, Uk, Uv, W1, W2,
                                                 Uq, Uo, Wgq, Wgk, W3, W4, wts);
  init_avg<<<16, 256, 0, stream>>>(out);
  vicsek_fused<<<ITEMS, 256, 0, stream>>>(
      agent_infos, nmask, pmask, wts, W_emb, b_emb,
      ln1g, ln1b, b1, b2, ln2g, ln2b, ln3g, ln3b,
      b3, b4, ln4g, ln4b, out);
}